// Round 3
// baseline (9261.278 us; speedup 1.0000x reference)
//
#include <hip/hip_runtime.h>
#include <stdint.h>

// ---------------------------------------------------------------------------
// VarianceAdaptor on MI355X — round 3: f32 outputs (d_out is float*), fused
// predictors, conv2 zero-padding fix. B=16, T=512, H=F=384, K=3, ML=4096.
// Compute runs in bf16 (canon in ws) with f32 accumulation; all 7 outputs are
// written as float32 at the concatenated-flat offsets.
// ---------------------------------------------------------------------------

using u16 = unsigned short;
using u32 = unsigned int;

#define DEV static __device__ __forceinline__

DEV float bf2f(u16 u) { union { u32 i; float f; } v; v.i = ((u32)u) << 16; return v.f; }
DEV u16 f2bf(float f) {
  union { float f; u32 i; } v; v.f = f;
  u32 x = v.i;
  return (u16)((x + 0x7FFFu + ((x >> 16) & 1u)) >> 16);   // RNE
}
DEV float lof(u32 p) { union { u32 i; float f; } v; v.i = p << 16; return v.f; }
DEV float hif(u32 p) { union { u32 i; float f; } v; v.i = p & 0xFFFF0000u; return v.f; }

// ---- canonical bf16 scratch layout (element offsets), all 8-elem aligned ----
static constexpr int C_X    = 0;        // 3145728  x (B,T,H)
static constexpr int C_SP   = 3145728;  // 8192
static constexpr int C_SE   = 3153920;  // 8192
static constexpr int C_DCW  = 3162112;  // 884736 (2,3,384,384)
static constexpr int C_DCB  = 4046848;  // 768
static constexpr int C_DCG  = 4047616;  // 768
static constexpr int C_DCBE = 4048384;  // 768
static constexpr int C_DLW  = 4049152;  // 384
static constexpr int C_DLB  = 4049536;  // 1 (pad 8)
static constexpr int C_PCW  = 4049544;
static constexpr int C_PCB  = 4934280;
static constexpr int C_PCG  = 4935048;
static constexpr int C_PCBE = 4935816;
static constexpr int C_PLW  = 4936584;
static constexpr int C_PLB  = 4936968;  // pad 8
static constexpr int C_ECW  = 4936976;
static constexpr int C_ECB  = 5821712;
static constexpr int C_ECG  = 5822480;
static constexpr int C_ECBE = 5823248;
static constexpr int C_ELW  = 5824016;
static constexpr int C_ELB  = 5824400;  // pad 8
static constexpr int C_PC1W = 5824408;
static constexpr int C_PC1B = 5824792;
static constexpr int C_EC1W = 5825176;
static constexpr int C_EC1B = 5825560;
static constexpr int C_PC2W = 5825944;
static constexpr int C_PC2B = 5826328;
static constexpr int C_EC2W = 5826712;
static constexpr int C_EC2B = 5827096;
static constexpr int C_END  = 5827480;

__device__ const int g_off[30] = {
  C_X, C_SP, C_SE, C_DCW, C_DCB, C_DCG, C_DCBE, C_DLW, C_DLB,
  C_PCW, C_PCB, C_PCG, C_PCBE, C_PLW, C_PLB,
  C_ECW, C_ECB, C_ECG, C_ECBE, C_ELW, C_ELB,
  C_PC1W, C_PC1B, C_EC1W, C_EC1B, C_PC2W, C_PC2B, C_EC2W, C_EC2B, C_END };
__device__ const int g_act[29] = {
  3145728, 8192, 8192, 884736, 768, 768, 768, 384, 1,
  884736, 768, 768, 768, 384, 1,
  884736, 768, 768, 768, 384, 1,
  384, 384, 384, 384, 384, 384, 384, 384 };

struct Srcs { const void* p[29]; };

// ---- dtype probe: f32 words' low halves rarely look like plausible bf16 ----
__global__ __launch_bounds__(256) void k_detect(const u32* __restrict__ x, int* __restrict__ flag) {
  __shared__ int sh[256];
  int t = threadIdx.x, cnt = 0;
  for (int i = t; i < 2048; i += 256) {
    u32 w = x[i];
    u32 lo = w & 0xFFFFu;
    float a = fabsf(lof(lo));
    if (lo == 0u || (a > 1e-5f && a < 1000.0f)) cnt++;
  }
  sh[t] = cnt; __syncthreads();
  for (int o = 128; o; o >>= 1) { if (t < o) sh[t] += sh[t + o]; __syncthreads(); }
  if (t == 0) *flag = (sh[0] > 1024) ? 1 : 0;
}

// ---- canonicalize all float inputs to one bf16 region ----------------------
__global__ __launch_bounds__(256) void k_canon(Srcs s, u16* __restrict__ canon, const int* __restrict__ flag) {
  int isbf = *flag;
  int stride = gridDim.x * blockDim.x;
  for (int i = blockIdx.x * blockDim.x + threadIdx.x; i < C_END; i += stride) {
    int lo = 0, hi = 29;
    while (hi - lo > 1) { int m = (lo + hi) >> 1; if (i >= g_off[m]) lo = m; else hi = m; }
    int li = i - g_off[lo];
    u16 v = 0;
    if (li < g_act[lo]) {
      if (isbf) v = ((const u16*)s.p[lo])[li];
      else      v = f2bf(((const float*)s.p[lo])[li]);
    }
    canon[i] = v;
  }
}

// ---- cumsum + (f32) src_duration / mel_len / mel_mask outputs --------------
__global__ __launch_bounds__(512) void k_prep(const int* __restrict__ dur, int* __restrict__ cum,
    int* __restrict__ melLenI, float* __restrict__ oDur, float* __restrict__ oML,
    float* __restrict__ oMask) {
  __shared__ int s[512];
  int b = blockIdx.x, t = threadIdx.x;
  int d = dur[b * 512 + t];
  s[t] = d; __syncthreads();
  for (int o = 1; o < 512; o <<= 1) {
    int v = s[t] + ((t >= o) ? s[t - o] : 0);
    __syncthreads(); s[t] = v; __syncthreads();
  }
  cum[b * 512 + t] = s[t];
  int mel = s[511];
  if (t == 0) { melLenI[b] = mel; oML[b] = (float)mel; }
  oDur[b * 512 + t] = (float)d;
  for (int j = t; j < 4096; j += 512) oMask[b * 4096 + j] = (j >= mel) ? 1.0f : 0.0f;
}

// ---- gather index: idx = min(upper_bound(cum, t), T-1) ----------------------
__global__ __launch_bounds__(256) void k_idx(const int* __restrict__ cum, int* __restrict__ idx) {
  int b = blockIdx.y;
  int t = blockIdx.x * 256 + threadIdx.x;
  const int* c = cum + b * 512;
  int lo = 0, hi = 512;
  while (lo < hi) { int m = (lo + hi) >> 1; if (c[m] <= t) lo = m + 1; else hi = m; }
  if (lo > 511) lo = 511;
  idx[b * 4096 + t] = lo;
}

// ---------------------------------------------------------------------------
// Fused predictor: 384 threads (1/out-channel), 32 timesteps/block.
// MODE 0: rows = X[b,t,:]           (duration branch, L=512)
// MODE 1: rows = t<mel ? X[b,idx]+S[b,idx]*C1W+C1B : 0   (pitch/energy, L=4096)
// conv1+bias+relu+LN (zeroed outside [0,L)) -> conv2+bias+relu+LN -> linear.
// ---------------------------------------------------------------------------
template<int L, int MODE, bool MASK>
__global__ __launch_bounds__(384, 2) void k_pred(
    const u16* __restrict__ X, const u16* __restrict__ S,
    const u16* __restrict__ C1W, const u16* __restrict__ C1B,
    const int* __restrict__ idx, const int* __restrict__ melLenI,
    const u16* __restrict__ W,                     // layer stride 442368
    const u16* __restrict__ CB, const u16* __restrict__ CG, const u16* __restrict__ CBE, // stride 384
    const u16* __restrict__ LW, const u16* __restrict__ LB,
    float* __restrict__ predF) {
  constexpr int TT  = 32;
  constexpr int R1  = TT + 2;   // conv1 output rows (t0-1 .. t0+TT)
  constexpr int RIN = TT + 4;   // input rows (t0-2 .. t0+TT+1)
  __shared__ u16 s_in[RIN * 384];   // input tile; later reused as h2
  __shared__ u16 s_h1[R1 * 384];    // conv1 y, then LN'd h1
  __shared__ float s_m[R1], s_r[R1];

  int b = blockIdx.y, t0 = blockIdx.x * TT, f = threadIdx.x;
  int mel = melLenI[b];

  // --- 1. load input rows [t0-2, t0+TT+2) ---
  if constexpr (MODE == 0) {
    #pragma unroll
    for (int r = 0; r < RIN; ++r) {
      int t = t0 - 2 + r;
      s_in[r * 384 + f] = (t >= 0 && t < L) ? X[((size_t)b * L + t) * 384 + f] : (u16)0;
    }
  } else {
    float c1wf = bf2f(C1W[f]), c1bf = bf2f(C1B[f]);
    #pragma unroll
    for (int r = 0; r < RIN; ++r) {
      int t = t0 - 2 + r;
      u16 v = 0;
      if (t >= 0 && t < L && t < mel) {
        int j = idx[b * L + t];
        float xv = bf2f(X[((size_t)b * 512 + j) * 384 + f]);
        float sv = bf2f(S[b * 512 + j]);
        v = f2bf(xv + sv * c1wf + c1bf);
      }
      s_in[r * 384 + f] = v;
    }
  }
  __syncthreads();

  int wv = f >> 6, lane = f & 63;

  // --- 2. conv1 (out rows t0-1 .. t0+TT) ---
  float acc1[R1];
  #pragma unroll
  for (int r = 0; r < R1; ++r) acc1[r] = 0.f;
  for (int c = 0; c < 384; c += 4) {
    float w[3][4];
    #pragma unroll
    for (int k = 0; k < 3; ++k)
      #pragma unroll
      for (int j = 0; j < 4; ++j)
        w[k][j] = bf2f(W[(k * 384 + c + j) * 384 + f]);
    #pragma unroll
    for (int r = 0; r < RIN; ++r) {
      uint2 rv = *(const uint2*)(s_in + r * 384 + c);
      float x0 = lof(rv.x), x1 = hif(rv.x), x2 = lof(rv.y), x3 = hif(rv.y);
      #pragma unroll
      for (int k = 0; k < 3; ++k) {
        int o = r - k;
        if (o >= 0 && o < R1) {
          acc1[o] = fmaf(x0, w[k][0], acc1[o]);
          acc1[o] = fmaf(x1, w[k][1], acc1[o]);
          acc1[o] = fmaf(x2, w[k][2], acc1[o]);
          acc1[o] = fmaf(x3, w[k][3], acc1[o]);
        }
      }
    }
  }

  // --- 3. bias+relu+LN layer 1; rows outside [0,L) are ZERO (conv2 padding) ---
  {
    float cb = bf2f(CB[f]), cg = bf2f(CG[f]), cbe = bf2f(CBE[f]);
    #pragma unroll
    for (int r = 0; r < R1; ++r) {
      float v = acc1[r] + cb; v = v > 0.f ? v : 0.f; acc1[r] = v;
      s_h1[r * 384 + f] = f2bf(v);
    }
    __syncthreads();
    for (int t = wv; t < R1; t += 6) {
      float s1 = 0.f, s2 = 0.f;
      #pragma unroll
      for (int i = 0; i < 6; ++i) { float v = bf2f(s_h1[t * 384 + i * 64 + lane]); s1 += v; s2 += v * v; }
      #pragma unroll
      for (int o = 32; o; o >>= 1) { s1 += __shfl_xor(s1, o); s2 += __shfl_xor(s2, o); }
      if (lane == 0) {
        float m = s1 * (1.f / 384.f);
        float var = s2 * (1.f / 384.f) - m * m; if (var < 0.f) var = 0.f;
        s_m[t] = m; s_r[t] = rsqrtf(var + 1e-5f);
      }
    }
    __syncthreads();
    #pragma unroll
    for (int r = 0; r < R1; ++r) {
      int t = t0 - 1 + r;
      bool valid = (t >= 0) && (t < L);
      s_h1[r * 384 + f] = valid ? f2bf((acc1[r] - s_m[r]) * s_r[r] * cg + cbe) : (u16)0;
    }
    __syncthreads();
  }

  // --- 4. conv2 (out rows t0 .. t0+TT) ---
  float acc2[TT];
  #pragma unroll
  for (int r = 0; r < TT; ++r) acc2[r] = 0.f;
  {
    const u16* W2 = W + 442368;
    for (int c = 0; c < 384; c += 4) {
      float w[3][4];
      #pragma unroll
      for (int k = 0; k < 3; ++k)
        #pragma unroll
        for (int j = 0; j < 4; ++j)
          w[k][j] = bf2f(W2[(k * 384 + c + j) * 384 + f]);
      #pragma unroll
      for (int r = 0; r < R1; ++r) {
        uint2 rv = *(const uint2*)(s_h1 + r * 384 + c);
        float x0 = lof(rv.x), x1 = hif(rv.x), x2 = lof(rv.y), x3 = hif(rv.y);
        #pragma unroll
        for (int k = 0; k < 3; ++k) {
          int o = r - k;
          if (o >= 0 && o < TT) {
            acc2[o] = fmaf(x0, w[k][0], acc2[o]);
            acc2[o] = fmaf(x1, w[k][1], acc2[o]);
            acc2[o] = fmaf(x2, w[k][2], acc2[o]);
            acc2[o] = fmaf(x3, w[k][3], acc2[o]);
          }
        }
      }
    }
  }

  // --- 5. bias+relu+LN layer 2 (h2 into s_in, free now) ---
  {
    float cb = bf2f(CB[384 + f]), cg = bf2f(CG[384 + f]), cbe = bf2f(CBE[384 + f]);
    #pragma unroll
    for (int r = 0; r < TT; ++r) {
      float v = acc2[r] + cb; v = v > 0.f ? v : 0.f; acc2[r] = v;
      s_in[r * 384 + f] = f2bf(v);
    }
    __syncthreads();
    for (int t = wv; t < TT; t += 6) {
      float s1 = 0.f, s2 = 0.f;
      #pragma unroll
      for (int i = 0; i < 6; ++i) { float v = bf2f(s_in[t * 384 + i * 64 + lane]); s1 += v; s2 += v * v; }
      #pragma unroll
      for (int o = 32; o; o >>= 1) { s1 += __shfl_xor(s1, o); s2 += __shfl_xor(s2, o); }
      if (lane == 0) {
        float m = s1 * (1.f / 384.f);
        float var = s2 * (1.f / 384.f) - m * m; if (var < 0.f) var = 0.f;
        s_m[t] = m; s_r[t] = rsqrtf(var + 1e-5f);
      }
    }
    __syncthreads();
    #pragma unroll
    for (int r = 0; r < TT; ++r)
      s_in[r * 384 + f] = f2bf((acc2[r] - s_m[r]) * s_r[r] * cg + cbe);
    __syncthreads();
  }

  // --- 6. linear 384->1 (+ mask), f32 out ---
  {
    float lwv[6];
    #pragma unroll
    for (int i = 0; i < 6; ++i) lwv[i] = bf2f(LW[i * 64 + lane]);
    float lb = bf2f(LB[0]);
    for (int t = wv; t < TT; t += 6) {
      float s = 0.f;
      #pragma unroll
      for (int i = 0; i < 6; ++i) s += bf2f(s_in[t * 384 + i * 64 + lane]) * lwv[i];
      #pragma unroll
      for (int o = 32; o; o >>= 1) s += __shfl_xor(s, o);
      if (lane == 0) {
        s += lb;
        int tt = t0 + t;
        if (MASK && tt >= mel) s = 0.f;
        predF[b * L + tt] = s;
      }
    }
  }
}

// ---- final: out = x_exp + pp*pc2w + pc2b + ep*ec2w + ec2b  (f32 out) -------
__global__ __launch_bounds__(256) void k_out(const u16* __restrict__ X,
    const int* __restrict__ idx, const int* __restrict__ melLenI,
    const float* __restrict__ ppF, const float* __restrict__ epF,
    const u16* __restrict__ W1, const u16* __restrict__ B1,
    const u16* __restrict__ W2, const u16* __restrict__ B2,
    float* __restrict__ outp) {
  int i = blockIdx.x * 256 + threadIdx.x;      // 0 .. B*ML*96-1 (float4 units)
  int f4 = i % 96, row = i / 96;
  int b = row >> 12, t = row & 4095;
  float pp = ppF[row], ep = epF[row];
  uint2 w1 = *(const uint2*)(W1 + f4 * 4);
  uint2 b1 = *(const uint2*)(B1 + f4 * 4);
  uint2 w2 = *(const uint2*)(W2 + f4 * 4);
  uint2 b2 = *(const uint2*)(B2 + f4 * 4);
  float xv[4] = {0.f, 0.f, 0.f, 0.f};
  if (t < melLenI[b]) {
    int j = idx[row];
    uint2 xa = *(const uint2*)(X + (size_t)(b * 512 + j) * 384 + f4 * 4);
    xv[0] = lof(xa.x); xv[1] = hif(xa.x); xv[2] = lof(xa.y); xv[3] = hif(xa.y);
  }
  float4 o;
  o.x = xv[0] + pp * lof(w1.x) + lof(b1.x) + ep * lof(w2.x) + lof(b2.x);
  o.y = xv[1] + pp * hif(w1.x) + hif(b1.x) + ep * hif(w2.x) + hif(b2.x);
  o.z = xv[2] + pp * lof(w1.y) + lof(b1.y) + ep * lof(w2.y) + lof(b2.y);
  o.w = xv[3] + pp * hif(w1.y) + hif(b1.y) + ep * hif(w2.y) + hif(b2.y);
  *(float4*)(outp + (size_t)i * 4) = o;
}

// ---------------------------------------------------------------------------
extern "C" void kernel_launch(void* const* d_in, const int* in_sizes, int n_in,
                              void* d_out, int out_size, void* d_ws, size_t ws_size,
                              hipStream_t stream) {
  char* ws = (char*)d_ws;
  int*   flag    = (int*)(ws + 0);
  int*   cum     = (int*)(ws + 256);       // 32 KB
  int*   melLenI = (int*)(ws + 33280);     // 64 B
  int*   idx     = (int*)(ws + 33536);     // 256 KB
  u16*   canon   = (u16*)(ws + 295936);    // 11.65 MB -> ws total ~12 MB

  float* o_main = (float*)d_out;           // (B, ML, H) = 25,165,824
  float* o_pp   = o_main + 25165824;       // (B, ML)  65536
  float* o_ep   = o_pp + 65536;            // (B, ML)  65536
  float* o_ld   = o_ep + 65536;            // (B, T)   8192
  float* o_dur  = o_ld + 8192;             // (B, T)   8192
  float* o_ml   = o_dur + 8192;            // (B,)     16
  float* o_mask = o_ml + 16;               // (B, ML)  65536

  Srcs S;
  static const int sel[29] = {0, 1, 2, 8, 9, 10, 11, 12, 13, 14, 15, 16, 17, 18, 19,
                              20, 21, 22, 23, 24, 25, 26, 27, 28, 29, 30, 31, 32, 33};
  for (int i = 0; i < 29; ++i) S.p[i] = d_in[sel[i]];
  const int* dur = (const int*)d_in[4];

  k_detect<<<1, 256, 0, stream>>>((const u32*)d_in[0], flag);
  k_canon<<<2048, 256, 0, stream>>>(S, canon, flag);
  k_prep<<<16, 512, 0, stream>>>(dur, cum, melLenI, o_dur, o_ml, o_mask);
  k_idx<<<dim3(16, 16), 256, 0, stream>>>(cum, idx);

  const u16* X = canon + C_X;

  // duration predictor (direct rows, no mask) -> o_ld
  k_pred<512, 0, false><<<dim3(16, 16), 384, 0, stream>>>(
      X, nullptr, nullptr, nullptr, idx, melLenI,
      canon + C_DCW, canon + C_DCB, canon + C_DCG, canon + C_DCBE,
      canon + C_DLW, canon + C_DLB, o_ld);

  // pitch branch -> o_pp
  k_pred<4096, 1, true><<<dim3(128, 16), 384, 0, stream>>>(
      X, canon + C_SP, canon + C_PC1W, canon + C_PC1B, idx, melLenI,
      canon + C_PCW, canon + C_PCB, canon + C_PCG, canon + C_PCBE,
      canon + C_PLW, canon + C_PLB, o_pp);

  // energy branch -> o_ep
  k_pred<4096, 1, true><<<dim3(128, 16), 384, 0, stream>>>(
      X, canon + C_SE, canon + C_EC1W, canon + C_EC1B, idx, melLenI,
      canon + C_ECW, canon + C_ECB, canon + C_ECG, canon + C_ECBE,
      canon + C_ELW, canon + C_ELB, o_ep);

  // final assembly -> o_main (reads o_pp/o_ep)
  k_out<<<24576, 256, 0, stream>>>(X, idx, melLenI, o_pp, o_ep,
      canon + C_PC2W, canon + C_PC2B, canon + C_EC2W, canon + C_EC2B, o_main);
}

// Round 4
// 629.243 us; speedup vs baseline: 14.7181x; 14.7181x over previous
//
#include <hip/hip_runtime.h>
#include <stdint.h>

// ---------------------------------------------------------------------------
// VarianceAdaptor on MI355X — round 4: MFMA conv predictors.
// B=16, T=512, H=F=384, K=3, ML=4096. f32 outputs.
// Fused per-branch kernel: provider -> conv1(MFMA)+LN -> conv2(MFMA)+LN ->
// linear. Weights pre-swizzled to B-fragment-linear layout (k_wprep).
// ---------------------------------------------------------------------------

using u16 = unsigned short;
using u32 = unsigned int;
typedef __attribute__((ext_vector_type(8))) short bf16x8;
typedef __attribute__((ext_vector_type(4))) float f32x4;

#define DEV static __device__ __forceinline__

DEV float bf2f(u16 u) { union { u32 i; float f; } v; v.i = ((u32)u) << 16; return v.f; }
DEV u16 f2bf(float f) {
  union { float f; u32 i; } v; v.f = f;
  u32 x = v.i;
  return (u16)((x + 0x7FFFu + ((x >> 16) & 1u)) >> 16);   // RNE
}
DEV float lof(u32 p) { union { u32 i; float f; } v; v.i = p << 16; return v.f; }
DEV float hif(u32 p) { union { u32 i; float f; } v; v.i = p & 0xFFFF0000u; return v.f; }

// ---- canonical bf16 scratch layout (element offsets) ------------------------
static constexpr int C_X    = 0;
static constexpr int C_SP   = 3145728;
static constexpr int C_SE   = 3153920;
static constexpr int C_DCW  = 3162112;
static constexpr int C_DCB  = 4046848;
static constexpr int C_DCG  = 4047616;
static constexpr int C_DCBE = 4048384;
static constexpr int C_DLW  = 4049152;
static constexpr int C_DLB  = 4049536;
static constexpr int C_PCW  = 4049544;
static constexpr int C_PCB  = 4934280;
static constexpr int C_PCG  = 4935048;
static constexpr int C_PCBE = 4935816;
static constexpr int C_PLW  = 4936584;
static constexpr int C_PLB  = 4936968;
static constexpr int C_ECW  = 4936976;
static constexpr int C_ECB  = 5821712;
static constexpr int C_ECG  = 5822480;
static constexpr int C_ECBE = 5823248;
static constexpr int C_ELW  = 5824016;
static constexpr int C_ELB  = 5824400;
static constexpr int C_PC1W = 5824408;
static constexpr int C_PC1B = 5824792;
static constexpr int C_EC1W = 5825176;
static constexpr int C_EC1B = 5825560;
static constexpr int C_PC2W = 5825944;
static constexpr int C_PC2B = 5826328;
static constexpr int C_EC2W = 5826712;
static constexpr int C_EC2B = 5827096;
static constexpr int C_END  = 5827480;

__device__ const int g_off[30] = {
  C_X, C_SP, C_SE, C_DCW, C_DCB, C_DCG, C_DCBE, C_DLW, C_DLB,
  C_PCW, C_PCB, C_PCG, C_PCBE, C_PLW, C_PLB,
  C_ECW, C_ECB, C_ECG, C_ECBE, C_ELW, C_ELB,
  C_PC1W, C_PC1B, C_EC1W, C_EC1B, C_PC2W, C_PC2B, C_EC2W, C_EC2B, C_END };
__device__ const int g_act[29] = {
  3145728, 8192, 8192, 884736, 768, 768, 768, 384, 1,
  884736, 768, 768, 768, 384, 1,
  884736, 768, 768, 768, 384, 1,
  384, 384, 384, 384, 384, 384, 384, 384 };
__device__ const int g_wsrc[3] = { C_DCW, C_PCW, C_ECW };

struct Srcs { const void* p[29]; };

// ---- dtype probe ------------------------------------------------------------
__global__ __launch_bounds__(256) void k_detect(const u32* __restrict__ x, int* __restrict__ flag) {
  __shared__ int sh[256];
  int t = threadIdx.x, cnt = 0;
  for (int i = t; i < 2048; i += 256) {
    u32 w = x[i];
    u32 lo = w & 0xFFFFu;
    float a = fabsf(lof(lo));
    if (lo == 0u || (a > 1e-5f && a < 1000.0f)) cnt++;
  }
  sh[t] = cnt; __syncthreads();
  for (int o = 128; o; o >>= 1) { if (t < o) sh[t] += sh[t + o]; __syncthreads(); }
  if (t == 0) *flag = (sh[0] > 1024) ? 1 : 0;
}

// ---- canonicalize all float inputs to one bf16 region -----------------------
__global__ __launch_bounds__(256) void k_canon(Srcs s, u16* __restrict__ canon, const int* __restrict__ flag) {
  int isbf = *flag;
  int stride = gridDim.x * blockDim.x;
  for (int i = blockIdx.x * blockDim.x + threadIdx.x; i < C_END; i += stride) {
    int lo = 0, hi = 29;
    while (hi - lo > 1) { int m = (lo + hi) >> 1; if (i >= g_off[m]) lo = m; else hi = m; }
    int li = i - g_off[lo];
    u16 v = 0;
    if (li < g_act[lo]) {
      if (isbf) v = ((const u16*)s.p[lo])[li];
      else      v = f2bf(((const float*)s.p[lo])[li]);
    }
    canon[i] = v;
  }
}

// ---- weight swizzle: (ls,kk,f) -> B-fragment-linear -------------------------
// dst[((ls*36+ks)*24+nf)*512 + l*8 + j] = W[ls][kk=ks*32+(l>>4)*8+j][f=nf*16+(l&15)]
__global__ __launch_bounds__(256) void k_wprep(const u16* __restrict__ canon, u16* __restrict__ WF) {
  int g = blockIdx.x * 256 + threadIdx.x;       // 3*2*36*24*64 = 331776
  int l = g & 63; int rest = g >> 6;
  int nf = rest % 24; rest /= 24;
  int ks = rest % 36; rest /= 36;
  int ls = rest & 1;  int br = rest >> 1;
  if (br >= 3) return;
  const u16* src = canon + g_wsrc[br] + ls * 442368;
  int kk0 = ks * 32 + (l >> 4) * 8;
  int f = nf * 16 + (l & 15);
  u16* dst = WF + (size_t)br * 884736 + ((size_t)(ls * 36 + ks) * 24 + nf) * 512 + l * 8;
  #pragma unroll
  for (int j = 0; j < 8; ++j)
    dst[j] = src[(size_t)(kk0 + j) * 384 + f];
}

// ---- cumsum + f32 src_duration / mel_len / mel_mask outputs -----------------
__global__ __launch_bounds__(512) void k_prep(const int* __restrict__ dur, int* __restrict__ cum,
    int* __restrict__ melLenI, float* __restrict__ oDur, float* __restrict__ oML,
    float* __restrict__ oMask) {
  __shared__ int s[512];
  int b = blockIdx.x, t = threadIdx.x;
  int d = dur[b * 512 + t];
  s[t] = d; __syncthreads();
  for (int o = 1; o < 512; o <<= 1) {
    int v = s[t] + ((t >= o) ? s[t - o] : 0);
    __syncthreads(); s[t] = v; __syncthreads();
  }
  cum[b * 512 + t] = s[t];
  int mel = s[511];
  if (t == 0) { melLenI[b] = mel; oML[b] = (float)mel; }
  oDur[b * 512 + t] = (float)d;
  for (int j = t; j < 4096; j += 512) oMask[b * 4096 + j] = (j >= mel) ? 1.0f : 0.0f;
}

// ---- gather index -----------------------------------------------------------
__global__ __launch_bounds__(256) void k_idx(const int* __restrict__ cum, int* __restrict__ idx) {
  int b = blockIdx.y;
  int t = blockIdx.x * 256 + threadIdx.x;
  const int* c = cum + b * 512;
  int lo = 0, hi = 512;
  while (lo < hi) { int m = (lo + hi) >> 1; if (c[m] <= t) lo = m + 1; else hi = m; }
  if (lo > 511) lo = 511;
  idx[b * 4096 + t] = lo;
}

// ---- MFMA conv over one layer ----------------------------------------------
// A from LDS rows (stride 392), B from fragment-linear global weights.
template<int NMF>
DEV void do_conv(const u16* sb, const u16* __restrict__ wf,
                 f32x4 (&acc)[NMF][6], const int (&moff)[NMF],
                 int wn, int llo, int lhi, int l) {
  int arow = llo * 392 + lhi * 8;
  for (int ks = 0; ks < 36; ++ks) {
    int k = ks / 12, c0 = (ks % 12) * 32;
    bf16x8 a[NMF];
    #pragma unroll
    for (int mf = 0; mf < NMF; ++mf)
      a[mf] = *(const bf16x8*)(sb + (moff[mf] + k) * 392 + c0 + arow);
    const u16* wb = wf + (ks * 24 + wn * 6) * 512 + l * 8;
    #pragma unroll
    for (int nf = 0; nf < 6; ++nf) {
      bf16x8 bv = *(const bf16x8*)(wb + nf * 512);
      #pragma unroll
      for (int mf = 0; mf < NMF; ++mf)
        acc[mf][nf] = __builtin_amdgcn_mfma_f32_16x16x32_bf16(a[mf], bv, acc[mf][nf], 0, 0, 0);
    }
  }
}

// ---- bias+relu+LN epilogue: in-reg stats, write normalized bf16 h to LDS ----
template<int NMF, bool ZERO_EDGE>
DEV void ln_epilogue(f32x4 (&acc)[NMF][6], const int (&moff)[NMF],
    const u16* __restrict__ CBp, const u16* __restrict__ CGp, const u16* __restrict__ CBEp,
    u16* sb, float* sp1, float* sp2, float* sm, float* sr,
    int wn, int llo, int lhi, int tid, int nrows, int t0, int L) {
  int colb = wn * 96 + llo;
  float bias[6], gv[6], bev[6];
  #pragma unroll
  for (int nf = 0; nf < 6; ++nf) {
    bias[nf] = bf2f(CBp[colb + nf * 16]);
    gv[nf]   = bf2f(CGp[colb + nf * 16]);
    bev[nf]  = bf2f(CBEp[colb + nf * 16]);
  }
  #pragma unroll
  for (int mf = 0; mf < NMF; ++mf)
    #pragma unroll
    for (int nf = 0; nf < 6; ++nf)
      #pragma unroll
      for (int r = 0; r < 4; ++r) {
        float v = acc[mf][nf][r] + bias[nf];
        acc[mf][nf][r] = v > 0.f ? v : 0.f;
      }
  // partial stats: sum over this wave's 96 cols, reduce across llo
  #pragma unroll
  for (int mf = 0; mf < NMF; ++mf)
    #pragma unroll
    for (int r = 0; r < 4; ++r) {
      float p1 = 0.f, p2 = 0.f;
      #pragma unroll
      for (int nf = 0; nf < 6; ++nf) { float v = acc[mf][nf][r]; p1 += v; p2 += v * v; }
      #pragma unroll
      for (int m = 1; m <= 8; m <<= 1) { p1 += __shfl_xor(p1, m); p2 += __shfl_xor(p2, m); }
      if (llo == 0) {
        int row = moff[mf] + lhi * 4 + r;
        sp1[row * 4 + wn] = p1; sp2[row * 4 + wn] = p2;
      }
    }
  __syncthreads();
  if (tid < nrows) {
    float a = sp1[tid * 4] + sp1[tid * 4 + 1] + sp1[tid * 4 + 2] + sp1[tid * 4 + 3];
    float b = sp2[tid * 4] + sp2[tid * 4 + 1] + sp2[tid * 4 + 2] + sp2[tid * 4 + 3];
    float m = a * (1.f / 384.f);
    float var = b * (1.f / 384.f) - m * m; if (var < 0.f) var = 0.f;
    sm[tid] = m; sr[tid] = rsqrtf(var + 1e-5f);
  }
  __syncthreads();
  #pragma unroll
  for (int mf = 0; mf < NMF; ++mf)
    #pragma unroll
    for (int r = 0; r < 4; ++r) {
      int row = moff[mf] + lhi * 4 + r;
      float m = sm[row], rs = sr[row];
      bool valid = true;
      if (ZERO_EDGE) { int t = t0 - 1 + row; valid = (t >= 0) && (t < L); }
      #pragma unroll
      for (int nf = 0; nf < 6; ++nf) {
        float v = (acc[mf][nf][r] - m) * rs * gv[nf] + bev[nf];
        sb[row * 392 + colb + nf * 16] = valid ? f2bf(v) : (u16)0;
      }
    }
  __syncthreads();
}

// ---------------------------------------------------------------------------
// Fused MFMA predictor. 512 threads = 8 waves (2M x 4N). TT=64 rows/block.
// MODE 0: rows = X[b,t,:]; MODE 1: length-regulate + 1x1 conv.
// ---------------------------------------------------------------------------
template<int L, int MODE, bool MASK>
__global__ __launch_bounds__(512, 2) void k_pred(
    const u16* __restrict__ X, const u16* __restrict__ S,
    const u16* __restrict__ C1W, const u16* __restrict__ C1B,
    const int* __restrict__ idx, const int* __restrict__ melLenI,
    const u16* __restrict__ WF,                    // branch fragment weights
    const u16* __restrict__ CB, const u16* __restrict__ CG, const u16* __restrict__ CBE,
    const u16* __restrict__ LW, const u16* __restrict__ LB,
    float* __restrict__ predF) {
  __shared__ alignas(16) u16 s_buf[68 * 392];
  __shared__ float sp1[68 * 4], sp2[68 * 4], sm[68], sr[68];

  int tid = threadIdx.x;
  int w = tid >> 6, l = tid & 63;
  int llo = l & 15, lhi = l >> 4;
  int wm = w >> 2, wn = w & 3;
  int b = blockIdx.y, t0 = blockIdx.x * 64;
  int mel = melLenI[b];

  // --- provider: fill s_buf rows 0..67 (t = t0-2+r) ---
  if constexpr (MODE == 0) {
    for (int i = 0; i < 9; ++i) {
      int r = w + i * 8;
      if (r < 68) {
        int t = t0 - 2 + r;
        bool valid = (t >= 0) && (t < L);
        const u16* xr = X + ((size_t)b * L + (valid ? t : 0)) * 384;
        #pragma unroll
        for (int c = 0; c < 6; ++c) {
          int col = l + c * 64;
          s_buf[r * 392 + col] = valid ? xr[col] : (u16)0;
        }
      }
    }
  } else {
    float c1wf[6], c1bf[6];
    #pragma unroll
    for (int c = 0; c < 6; ++c) { c1wf[c] = bf2f(C1W[l + c * 64]); c1bf[c] = bf2f(C1B[l + c * 64]); }
    for (int i = 0; i < 9; ++i) {
      int r = w + i * 8;
      if (r < 68) {
        int t = t0 - 2 + r;
        bool valid = (t >= 0) && (t < L) && (t < mel);
        int j = valid ? idx[b * L + t] : 0;
        float sv = valid ? bf2f(S[b * 512 + j]) : 0.f;
        const u16* xr = X + ((size_t)b * 512 + j) * 384;
        #pragma unroll
        for (int c = 0; c < 6; ++c) {
          int col = l + c * 64;
          float v = bf2f(xr[col]) + sv * c1wf[c] + c1bf[c];
          s_buf[r * 392 + col] = valid ? f2bf(v) : (u16)0;
        }
      }
    }
  }
  __syncthreads();

  // --- conv1 + LN (output rows 0..65 ~ t = t0-1+row) ---
  if (wm == 0) {
    const int moff[3] = {0, 16, 32};
    f32x4 acc[3][6];
    #pragma unroll
    for (int mf = 0; mf < 3; ++mf)
      #pragma unroll
      for (int nf = 0; nf < 6; ++nf) acc[mf][nf] = (f32x4){0.f, 0.f, 0.f, 0.f};
    do_conv<3>(s_buf, WF, acc, moff, wn, llo, lhi, l);
    ln_epilogue<3, true>(acc, moff, CB, CG, CBE, s_buf, sp1, sp2, sm, sr,
                         wn, llo, lhi, tid, 66, t0, L);
  } else {
    const int moff[2] = {48, 50};
    f32x4 acc[2][6];
    #pragma unroll
    for (int mf = 0; mf < 2; ++mf)
      #pragma unroll
      for (int nf = 0; nf < 6; ++nf) acc[mf][nf] = (f32x4){0.f, 0.f, 0.f, 0.f};
    do_conv<2>(s_buf, WF, acc, moff, wn, llo, lhi, l);
    ln_epilogue<2, true>(acc, moff, CB, CG, CBE, s_buf, sp1, sp2, sm, sr,
                         wn, llo, lhi, tid, 66, t0, L);
  }

  // --- conv2 + LN (output rows 0..63 ~ t = t0+row) ---
  {
    f32x4 acc[2][6];
    #pragma unroll
    for (int mf = 0; mf < 2; ++mf)
      #pragma unroll
      for (int nf = 0; nf < 6; ++nf) acc[mf][nf] = (f32x4){0.f, 0.f, 0.f, 0.f};
    if (wm == 0) {
      const int moff[2] = {0, 16};
      do_conv<2>(s_buf, WF + 442368, acc, moff, wn, llo, lhi, l);
      ln_epilogue<2, false>(acc, moff, CB + 384, CG + 384, CBE + 384, s_buf,
                            sp1, sp2, sm, sr, wn, llo, lhi, tid, 64, t0, L);
    } else {
      const int moff[2] = {32, 48};
      do_conv<2>(s_buf, WF + 442368, acc, moff, wn, llo, lhi, l);
      ln_epilogue<2, false>(acc, moff, CB + 384, CG + 384, CBE + 384, s_buf,
                            sp1, sp2, sm, sr, wn, llo, lhi, tid, 64, t0, L);
    }
  }

  // --- linear 384->1 (+ mask) ---
  {
    float lwv[6];
    #pragma unroll
    for (int c = 0; c < 6; ++c) lwv[c] = bf2f(LW[l + c * 64]);
    float lb = bf2f(LB[0]);
    for (int i = 0; i < 8; ++i) {
      int r = w + i * 8;
      float s = 0.f;
      #pragma unroll
      for (int c = 0; c < 6; ++c) s += bf2f(s_buf[r * 392 + l + c * 64]) * lwv[c];
      #pragma unroll
      for (int o = 32; o; o >>= 1) s += __shfl_xor(s, o);
      if (l == 0) {
        s += lb;
        int tt = t0 + r;
        if (MASK && tt >= mel) s = 0.f;
        predF[b * L + tt] = s;
      }
    }
  }
}

// ---- final: out = x_exp + pp*pc2w + pc2b + ep*ec2w + ec2b  (f32 out) -------
__global__ __launch_bounds__(256) void k_out(const u16* __restrict__ X,
    const int* __restrict__ idx, const int* __restrict__ melLenI,
    const float* __restrict__ ppF, const float* __restrict__ epF,
    const u16* __restrict__ W1, const u16* __restrict__ B1,
    const u16* __restrict__ W2, const u16* __restrict__ B2,
    float* __restrict__ outp) {
  int i = blockIdx.x * 256 + threadIdx.x;      // float4 units
  int f4 = i % 96, row = i / 96;
  int b = row >> 12, t = row & 4095;
  float pp = ppF[row], ep = epF[row];
  uint2 w1 = *(const uint2*)(W1 + f4 * 4);
  uint2 b1 = *(const uint2*)(B1 + f4 * 4);
  uint2 w2 = *(const uint2*)(W2 + f4 * 4);
  uint2 b2 = *(const uint2*)(B2 + f4 * 4);
  float xv[4] = {0.f, 0.f, 0.f, 0.f};
  if (t < melLenI[b]) {
    int j = idx[row];
    uint2 xa = *(const uint2*)(X + (size_t)(b * 512 + j) * 384 + f4 * 4);
    xv[0] = lof(xa.x); xv[1] = hif(xa.x); xv[2] = lof(xa.y); xv[3] = hif(xa.y);
  }
  float4 o;
  o.x = xv[0] + pp * lof(w1.x) + lof(b1.x) + ep * lof(w2.x) + lof(b2.x);
  o.y = xv[1] + pp * hif(w1.x) + hif(b1.x) + ep * hif(w2.x) + hif(b2.x);
  o.z = xv[2] + pp * lof(w1.y) + lof(b1.y) + ep * lof(w2.y) + lof(b2.y);
  o.w = xv[3] + pp * hif(w1.y) + hif(b1.y) + ep * hif(w2.y) + hif(b2.y);
  *(float4*)(outp + (size_t)i * 4) = o;
}

// ---------------------------------------------------------------------------
extern "C" void kernel_launch(void* const* d_in, const int* in_sizes, int n_in,
                              void* d_out, int out_size, void* d_ws, size_t ws_size,
                              hipStream_t stream) {
  char* ws = (char*)d_ws;
  int*   flag    = (int*)(ws + 0);
  int*   cum     = (int*)(ws + 256);
  int*   melLenI = (int*)(ws + 33280);
  int*   idx     = (int*)(ws + 33536);
  u16*   canon   = (u16*)(ws + 295936);        // 11,654,960 B
  u16*   WF      = (u16*)(ws + 11950896);      //  5,308,416 B (3 branches) -> ~17.3 MB total

  float* o_main = (float*)d_out;               // (B, ML, H)
  float* o_pp   = o_main + 25165824;           // (B, ML)
  float* o_ep   = o_pp + 65536;                // (B, ML)
  float* o_ld   = o_ep + 65536;                // (B, T)
  float* o_dur  = o_ld + 8192;                 // (B, T)
  float* o_ml   = o_dur + 8192;                // (B,)
  float* o_mask = o_ml + 16;                   // (B, ML)

  Srcs S;
  static const int sel[29] = {0, 1, 2, 8, 9, 10, 11, 12, 13, 14, 15, 16, 17, 18, 19,
                              20, 21, 22, 23, 24, 25, 26, 27, 28, 29, 30, 31, 32, 33};
  for (int i = 0; i < 29; ++i) S.p[i] = d_in[sel[i]];
  const int* dur = (const int*)d_in[4];

  k_detect<<<1, 256, 0, stream>>>((const u32*)d_in[0], flag);
  k_canon<<<2048, 256, 0, stream>>>(S, canon, flag);
  k_wprep<<<1296, 256, 0, stream>>>(canon, WF);
  k_prep<<<16, 512, 0, stream>>>(dur, cum, melLenI, o_dur, o_ml, o_mask);
  k_idx<<<dim3(16, 16), 256, 0, stream>>>(cum, idx);

  const u16* X = canon + C_X;

  // duration predictor -> o_ld
  k_pred<512, 0, false><<<dim3(8, 16), 512, 0, stream>>>(
      X, nullptr, nullptr, nullptr, idx, melLenI,
      WF + 0 * 884736, canon + C_DCB, canon + C_DCG, canon + C_DCBE,
      canon + C_DLW, canon + C_DLB, o_ld);

  // pitch branch -> o_pp
  k_pred<4096, 1, true><<<dim3(64, 16), 512, 0, stream>>>(
      X, canon + C_SP, canon + C_PC1W, canon + C_PC1B, idx, melLenI,
      WF + 1 * 884736, canon + C_PCB, canon + C_PCG, canon + C_PCBE,
      canon + C_PLW, canon + C_PLB, o_pp);

  // energy branch -> o_ep
  k_pred<4096, 1, true><<<dim3(64, 16), 512, 0, stream>>>(
      X, canon + C_SE, canon + C_EC1W, canon + C_EC1B, idx, melLenI,
      WF + 2 * 884736, canon + C_ECB, canon + C_ECG, canon + C_ECBE,
      canon + C_ELW, canon + C_ELB, o_ep);

  // final assembly -> o_main
  k_out<<<24576, 256, 0, stream>>>(X, idx, melLenI, o_pp, o_ep,
      canon + C_PC2W, canon + C_PC2B, canon + C_EC2W, canon + C_EC2B, o_main);
}

// Round 5
// 461.687 us; speedup vs baseline: 20.0597x; 1.3629x over previous
//
#include <hip/hip_runtime.h>
#include <stdint.h>

// ---------------------------------------------------------------------------
// VarianceAdaptor on MI355X — round 5: software-pipelined MFMA conv.
// Changes vs r4: 3-deep B-frag / 2-deep A-frag register pipeline in do_conv,
// s_setprio around MFMA clusters, pitch+energy merged into one launch (z-dim).
// ---------------------------------------------------------------------------

using u16 = unsigned short;
using u32 = unsigned int;
typedef __attribute__((ext_vector_type(8))) short bf16x8;
typedef __attribute__((ext_vector_type(4))) float f32x4;

#define DEV static __device__ __forceinline__

DEV float bf2f(u16 u) { union { u32 i; float f; } v; v.i = ((u32)u) << 16; return v.f; }
DEV u16 f2bf(float f) {
  union { float f; u32 i; } v; v.f = f;
  u32 x = v.i;
  return (u16)((x + 0x7FFFu + ((x >> 16) & 1u)) >> 16);   // RNE
}
DEV float lof(u32 p) { union { u32 i; float f; } v; v.i = p << 16; return v.f; }
DEV float hif(u32 p) { union { u32 i; float f; } v; v.i = p & 0xFFFF0000u; return v.f; }

// ---- canonical bf16 scratch layout (element offsets) ------------------------
static constexpr int C_X    = 0;
static constexpr int C_SP   = 3145728;
static constexpr int C_SE   = 3153920;
static constexpr int C_DCW  = 3162112;
static constexpr int C_DCB  = 4046848;
static constexpr int C_DCG  = 4047616;
static constexpr int C_DCBE = 4048384;
static constexpr int C_DLW  = 4049152;
static constexpr int C_DLB  = 4049536;
static constexpr int C_PCW  = 4049544;
static constexpr int C_PCB  = 4934280;
static constexpr int C_PCG  = 4935048;
static constexpr int C_PCBE = 4935816;
static constexpr int C_PLW  = 4936584;
static constexpr int C_PLB  = 4936968;
static constexpr int C_ECW  = 4936976;
static constexpr int C_ECB  = 5821712;
static constexpr int C_ECG  = 5822480;
static constexpr int C_ECBE = 5823248;
static constexpr int C_ELW  = 5824016;
static constexpr int C_ELB  = 5824400;
static constexpr int C_PC1W = 5824408;
static constexpr int C_PC1B = 5824792;
static constexpr int C_EC1W = 5825176;
static constexpr int C_EC1B = 5825560;
static constexpr int C_PC2W = 5825944;
static constexpr int C_PC2B = 5826328;
static constexpr int C_EC2W = 5826712;
static constexpr int C_EC2B = 5827096;
static constexpr int C_END  = 5827480;

__device__ const int g_off[30] = {
  C_X, C_SP, C_SE, C_DCW, C_DCB, C_DCG, C_DCBE, C_DLW, C_DLB,
  C_PCW, C_PCB, C_PCG, C_PCBE, C_PLW, C_PLB,
  C_ECW, C_ECB, C_ECG, C_ECBE, C_ELW, C_ELB,
  C_PC1W, C_PC1B, C_EC1W, C_EC1B, C_PC2W, C_PC2B, C_EC2W, C_EC2B, C_END };
__device__ const int g_act[29] = {
  3145728, 8192, 8192, 884736, 768, 768, 768, 384, 1,
  884736, 768, 768, 768, 384, 1,
  884736, 768, 768, 768, 384, 1,
  384, 384, 384, 384, 384, 384, 384, 384 };
__device__ const int g_wsrc[3] = { C_DCW, C_PCW, C_ECW };

struct Srcs { const void* p[29]; };

struct BranchArgs {
  const u16 *S, *C1W, *C1B, *WF, *CB, *CG, *CBE, *LW, *LB;
  float* predF;
};

// ---- dtype probe ------------------------------------------------------------
__global__ __launch_bounds__(256) void k_detect(const u32* __restrict__ x, int* __restrict__ flag) {
  __shared__ int sh[256];
  int t = threadIdx.x, cnt = 0;
  for (int i = t; i < 2048; i += 256) {
    u32 w = x[i];
    u32 lo = w & 0xFFFFu;
    float a = fabsf(lof(lo));
    if (lo == 0u || (a > 1e-5f && a < 1000.0f)) cnt++;
  }
  sh[t] = cnt; __syncthreads();
  for (int o = 128; o; o >>= 1) { if (t < o) sh[t] += sh[t + o]; __syncthreads(); }
  if (t == 0) *flag = (sh[0] > 1024) ? 1 : 0;
}

// ---- canonicalize all float inputs to one bf16 region -----------------------
__global__ __launch_bounds__(256) void k_canon(Srcs s, u16* __restrict__ canon, const int* __restrict__ flag) {
  int isbf = *flag;
  int stride = gridDim.x * blockDim.x;
  for (int i = blockIdx.x * blockDim.x + threadIdx.x; i < C_END; i += stride) {
    int lo = 0, hi = 29;
    while (hi - lo > 1) { int m = (lo + hi) >> 1; if (i >= g_off[m]) lo = m; else hi = m; }
    int li = i - g_off[lo];
    u16 v = 0;
    if (li < g_act[lo]) {
      if (isbf) v = ((const u16*)s.p[lo])[li];
      else      v = f2bf(((const float*)s.p[lo])[li]);
    }
    canon[i] = v;
  }
}

// ---- weight swizzle: (ls,kk,f) -> B-fragment-linear -------------------------
__global__ __launch_bounds__(256) void k_wprep(const u16* __restrict__ canon, u16* __restrict__ WF) {
  int g = blockIdx.x * 256 + threadIdx.x;       // 3*2*36*24*64 = 331776
  int l = g & 63; int rest = g >> 6;
  int nf = rest % 24; rest /= 24;
  int ks = rest % 36; rest /= 36;
  int ls = rest & 1;  int br = rest >> 1;
  if (br >= 3) return;
  const u16* src = canon + g_wsrc[br] + ls * 442368;
  int kk0 = ks * 32 + (l >> 4) * 8;
  int f = nf * 16 + (l & 15);
  u16* dst = WF + (size_t)br * 884736 + ((size_t)(ls * 36 + ks) * 24 + nf) * 512 + l * 8;
  #pragma unroll
  for (int j = 0; j < 8; ++j)
    dst[j] = src[(size_t)(kk0 + j) * 384 + f];
}

// ---- cumsum + f32 src_duration / mel_len / mel_mask outputs -----------------
__global__ __launch_bounds__(512) void k_prep(const int* __restrict__ dur, int* __restrict__ cum,
    int* __restrict__ melLenI, float* __restrict__ oDur, float* __restrict__ oML,
    float* __restrict__ oMask) {
  __shared__ int s[512];
  int b = blockIdx.x, t = threadIdx.x;
  int d = dur[b * 512 + t];
  s[t] = d; __syncthreads();
  for (int o = 1; o < 512; o <<= 1) {
    int v = s[t] + ((t >= o) ? s[t - o] : 0);
    __syncthreads(); s[t] = v; __syncthreads();
  }
  cum[b * 512 + t] = s[t];
  int mel = s[511];
  if (t == 0) { melLenI[b] = mel; oML[b] = (float)mel; }
  oDur[b * 512 + t] = (float)d;
  for (int j = t; j < 4096; j += 512) oMask[b * 4096 + j] = (j >= mel) ? 1.0f : 0.0f;
}

// ---- gather index -----------------------------------------------------------
__global__ __launch_bounds__(256) void k_idx(const int* __restrict__ cum, int* __restrict__ idx) {
  int b = blockIdx.y;
  int t = blockIdx.x * 256 + threadIdx.x;
  const int* c = cum + b * 512;
  int lo = 0, hi = 512;
  while (lo < hi) { int m = (lo + hi) >> 1; if (c[m] <= t) lo = m + 1; else hi = m; }
  if (lo > 511) lo = 511;
  idx[b * 4096 + t] = lo;
}

// ---- MFMA conv, software-pipelined: B 3-deep, A 2-deep ----------------------
template<int NMF>
DEV void do_conv(const u16* sb, const u16* __restrict__ wf,
                 f32x4 (&acc)[NMF][6], const int (&moff)[NMF],
                 int wn, int llo, int lhi, int l) {
  int arow = llo * 392 + lhi * 8;
  const u16* wb = wf + wn * 6 * 512 + l * 8;
  bf16x8 ab[2][NMF];
  bf16x8 bb[3][6];
  #pragma unroll
  for (int mf = 0; mf < NMF; ++mf)
    ab[0][mf] = *(const bf16x8*)(sb + moff[mf] * 392 + arow);           // ks=0
  #pragma unroll
  for (int nf = 0; nf < 6; ++nf) {
    bb[0][nf] = *(const bf16x8*)(wb + nf * 512);                         // ks=0
    bb[1][nf] = *(const bf16x8*)(wb + (24 + nf) * 512);                  // ks=1
  }
  #pragma unroll
  for (int ks = 0; ks < 36; ++ks) {
    if (ks + 2 < 36) {                       // prefetch B for ks+2 (L2 latency)
      #pragma unroll
      for (int nf = 0; nf < 6; ++nf)
        bb[(ks + 2) % 3][nf] = *(const bf16x8*)(wb + ((ks + 2) * 24 + nf) * 512);
    }
    if (ks + 1 < 36) {                       // prefetch A for ks+1 (LDS latency)
      int k1 = (ks + 1) / 12, c1 = ((ks + 1) % 12) * 32;
      #pragma unroll
      for (int mf = 0; mf < NMF; ++mf)
        ab[(ks + 1) & 1][mf] = *(const bf16x8*)(sb + (moff[mf] + k1) * 392 + c1 + arow);
    }
    __builtin_amdgcn_s_setprio(1);
    #pragma unroll
    for (int nf = 0; nf < 6; ++nf)
      #pragma unroll
      for (int mf = 0; mf < NMF; ++mf)
        acc[mf][nf] = __builtin_amdgcn_mfma_f32_16x16x32_bf16(ab[ks & 1][mf], bb[ks % 3][nf], acc[mf][nf], 0, 0, 0);
    __builtin_amdgcn_s_setprio(0);
  }
}

// ---- bias+relu+LN epilogue: in-reg stats, write normalized bf16 h to LDS ----
template<int NMF, bool ZERO_EDGE>
DEV void ln_epilogue(f32x4 (&acc)[NMF][6], const int (&moff)[NMF],
    const u16* __restrict__ CBp, const u16* __restrict__ CGp, const u16* __restrict__ CBEp,
    u16* sb, float* sp1, float* sp2, float* sm, float* sr,
    int wn, int llo, int lhi, int tid, int nrows, int t0, int L) {
  int colb = wn * 96 + llo;
  float bias[6], gv[6], bev[6];
  #pragma unroll
  for (int nf = 0; nf < 6; ++nf) {
    bias[nf] = bf2f(CBp[colb + nf * 16]);
    gv[nf]   = bf2f(CGp[colb + nf * 16]);
    bev[nf]  = bf2f(CBEp[colb + nf * 16]);
  }
  #pragma unroll
  for (int mf = 0; mf < NMF; ++mf)
    #pragma unroll
    for (int nf = 0; nf < 6; ++nf)
      #pragma unroll
      for (int r = 0; r < 4; ++r) {
        float v = acc[mf][nf][r] + bias[nf];
        acc[mf][nf][r] = v > 0.f ? v : 0.f;
      }
  #pragma unroll
  for (int mf = 0; mf < NMF; ++mf)
    #pragma unroll
    for (int r = 0; r < 4; ++r) {
      float p1 = 0.f, p2 = 0.f;
      #pragma unroll
      for (int nf = 0; nf < 6; ++nf) { float v = acc[mf][nf][r]; p1 += v; p2 += v * v; }
      #pragma unroll
      for (int m = 1; m <= 8; m <<= 1) { p1 += __shfl_xor(p1, m); p2 += __shfl_xor(p2, m); }
      if (llo == 0) {
        int row = moff[mf] + lhi * 4 + r;
        sp1[row * 4 + wn] = p1; sp2[row * 4 + wn] = p2;
      }
    }
  __syncthreads();
  if (tid < nrows) {
    float a = sp1[tid * 4] + sp1[tid * 4 + 1] + sp1[tid * 4 + 2] + sp1[tid * 4 + 3];
    float b = sp2[tid * 4] + sp2[tid * 4 + 1] + sp2[tid * 4 + 2] + sp2[tid * 4 + 3];
    float m = a * (1.f / 384.f);
    float var = b * (1.f / 384.f) - m * m; if (var < 0.f) var = 0.f;
    sm[tid] = m; sr[tid] = rsqrtf(var + 1e-5f);
  }
  __syncthreads();
  #pragma unroll
  for (int mf = 0; mf < NMF; ++mf)
    #pragma unroll
    for (int r = 0; r < 4; ++r) {
      int row = moff[mf] + lhi * 4 + r;
      float m = sm[row], rs = sr[row];
      bool valid = true;
      if (ZERO_EDGE) { int t = t0 - 1 + row; valid = (t >= 0) && (t < L); }
      #pragma unroll
      for (int nf = 0; nf < 6; ++nf) {
        float v = (acc[mf][nf][r] - m) * rs * gv[nf] + bev[nf];
        sb[row * 392 + colb + nf * 16] = valid ? f2bf(v) : (u16)0;
      }
    }
  __syncthreads();
}

// ---------------------------------------------------------------------------
// Fused MFMA predictor. 512 threads = 8 waves (2M x 4N). TT=64 rows/block.
// blockIdx.z selects the branch (pitch / energy) arg set.
// ---------------------------------------------------------------------------
template<int L, int MODE, bool MASK>
__global__ __launch_bounds__(512, 2) void k_pred(
    const u16* __restrict__ X, const int* __restrict__ idx,
    const int* __restrict__ melLenI, BranchArgs arg0, BranchArgs arg1) {
  __shared__ alignas(16) u16 s_buf[68 * 392];
  __shared__ float sp1[68 * 4], sp2[68 * 4], sm[68], sr[68];

  const BranchArgs& ba = (blockIdx.z == 0) ? arg0 : arg1;

  int tid = threadIdx.x;
  int w = tid >> 6, l = tid & 63;
  int llo = l & 15, lhi = l >> 4;
  int wm = w >> 2, wn = w & 3;
  int b = blockIdx.y, t0 = blockIdx.x * 64;
  int mel = melLenI[b];

  // --- provider: fill s_buf rows 0..67 (t = t0-2+r) ---
  if constexpr (MODE == 0) {
    for (int i = 0; i < 9; ++i) {
      int r = w + i * 8;
      if (r < 68) {
        int t = t0 - 2 + r;
        bool valid = (t >= 0) && (t < L);
        const u16* xr = X + ((size_t)b * L + (valid ? t : 0)) * 384;
        #pragma unroll
        for (int c = 0; c < 6; ++c) {
          int col = l + c * 64;
          s_buf[r * 392 + col] = valid ? xr[col] : (u16)0;
        }
      }
    }
  } else {
    float c1wf[6], c1bf[6];
    #pragma unroll
    for (int c = 0; c < 6; ++c) { c1wf[c] = bf2f(ba.C1W[l + c * 64]); c1bf[c] = bf2f(ba.C1B[l + c * 64]); }
    for (int i = 0; i < 9; ++i) {
      int r = w + i * 8;
      if (r < 68) {
        int t = t0 - 2 + r;
        bool valid = (t >= 0) && (t < L) && (t < mel);
        int j = valid ? idx[b * L + t] : 0;
        float sv = valid ? bf2f(ba.S[b * 512 + j]) : 0.f;
        const u16* xr = X + ((size_t)b * 512 + j) * 384;
        #pragma unroll
        for (int c = 0; c < 6; ++c) {
          int col = l + c * 64;
          float v = bf2f(xr[col]) + sv * c1wf[c] + c1bf[c];
          s_buf[r * 392 + col] = valid ? f2bf(v) : (u16)0;
        }
      }
    }
  }
  __syncthreads();

  // --- conv1 + LN (output rows 0..65 ~ t = t0-1+row) ---
  if (wm == 0) {
    const int moff[3] = {0, 16, 32};
    f32x4 acc[3][6];
    #pragma unroll
    for (int mf = 0; mf < 3; ++mf)
      #pragma unroll
      for (int nf = 0; nf < 6; ++nf) acc[mf][nf] = (f32x4){0.f, 0.f, 0.f, 0.f};
    do_conv<3>(s_buf, ba.WF, acc, moff, wn, llo, lhi, l);
    ln_epilogue<3, true>(acc, moff, ba.CB, ba.CG, ba.CBE, s_buf, sp1, sp2, sm, sr,
                         wn, llo, lhi, tid, 66, t0, L);
  } else {
    const int moff[2] = {48, 50};
    f32x4 acc[2][6];
    #pragma unroll
    for (int mf = 0; mf < 2; ++mf)
      #pragma unroll
      for (int nf = 0; nf < 6; ++nf) acc[mf][nf] = (f32x4){0.f, 0.f, 0.f, 0.f};
    do_conv<2>(s_buf, ba.WF, acc, moff, wn, llo, lhi, l);
    ln_epilogue<2, true>(acc, moff, ba.CB, ba.CG, ba.CBE, s_buf, sp1, sp2, sm, sr,
                         wn, llo, lhi, tid, 66, t0, L);
  }

  // --- conv2 + LN (output rows 0..63 ~ t = t0+row) ---
  {
    f32x4 acc[2][6];
    #pragma unroll
    for (int mf = 0; mf < 2; ++mf)
      #pragma unroll
      for (int nf = 0; nf < 6; ++nf) acc[mf][nf] = (f32x4){0.f, 0.f, 0.f, 0.f};
    if (wm == 0) {
      const int moff[2] = {0, 16};
      do_conv<2>(s_buf, ba.WF + 442368, acc, moff, wn, llo, lhi, l);
      ln_epilogue<2, false>(acc, moff, ba.CB + 384, ba.CG + 384, ba.CBE + 384, s_buf,
                            sp1, sp2, sm, sr, wn, llo, lhi, tid, 64, t0, L);
    } else {
      const int moff[2] = {32, 48};
      do_conv<2>(s_buf, ba.WF + 442368, acc, moff, wn, llo, lhi, l);
      ln_epilogue<2, false>(acc, moff, ba.CB + 384, ba.CG + 384, ba.CBE + 384, s_buf,
                            sp1, sp2, sm, sr, wn, llo, lhi, tid, 64, t0, L);
    }
  }

  // --- linear 384->1 (+ mask) ---
  {
    float lwv[6];
    #pragma unroll
    for (int c = 0; c < 6; ++c) lwv[c] = bf2f(ba.LW[l + c * 64]);
    float lb = bf2f(ba.LB[0]);
    for (int i = 0; i < 8; ++i) {
      int r = w + i * 8;
      float s = 0.f;
      #pragma unroll
      for (int c = 0; c < 6; ++c) s += bf2f(s_buf[r * 392 + l + c * 64]) * lwv[c];
      #pragma unroll
      for (int o = 32; o; o >>= 1) s += __shfl_xor(s, o);
      if (l == 0) {
        s += lb;
        int tt = t0 + r;
        if (MASK && tt >= mel) s = 0.f;
        ba.predF[b * L + tt] = s;
      }
    }
  }
}

// ---- final: out = x_exp + pp*pc2w + pc2b + ep*ec2w + ec2b  (f32 out) -------
__global__ __launch_bounds__(256) void k_out(const u16* __restrict__ X,
    const int* __restrict__ idx, const int* __restrict__ melLenI,
    const float* __restrict__ ppF, const float* __restrict__ epF,
    const u16* __restrict__ W1, const u16* __restrict__ B1,
    const u16* __restrict__ W2, const u16* __restrict__ B2,
    float* __restrict__ outp) {
  int i = blockIdx.x * 256 + threadIdx.x;      // float4 units
  int f4 = i % 96, row = i / 96;
  int b = row >> 12, t = row & 4095;
  float pp = ppF[row], ep = epF[row];
  uint2 w1 = *(const uint2*)(W1 + f4 * 4);
  uint2 b1 = *(const uint2*)(B1 + f4 * 4);
  uint2 w2 = *(const uint2*)(W2 + f4 * 4);
  uint2 b2 = *(const uint2*)(B2 + f4 * 4);
  float xv[4] = {0.f, 0.f, 0.f, 0.f};
  if (t < melLenI[b]) {
    int j = idx[row];
    uint2 xa = *(const uint2*)(X + (size_t)(b * 512 + j) * 384 + f4 * 4);
    xv[0] = lof(xa.x); xv[1] = hif(xa.x); xv[2] = lof(xa.y); xv[3] = hif(xa.y);
  }
  float4 o;
  o.x = xv[0] + pp * lof(w1.x) + lof(b1.x) + ep * lof(w2.x) + lof(b2.x);
  o.y = xv[1] + pp * hif(w1.x) + hif(b1.x) + ep * hif(w2.x) + hif(b2.x);
  o.z = xv[2] + pp * lof(w1.y) + lof(b1.y) + ep * lof(w2.y) + lof(b2.y);
  o.w = xv[3] + pp * hif(w1.y) + hif(b1.y) + ep * hif(w2.y) + hif(b2.y);
  *(float4*)(outp + (size_t)i * 4) = o;
}

// ---------------------------------------------------------------------------
extern "C" void kernel_launch(void* const* d_in, const int* in_sizes, int n_in,
                              void* d_out, int out_size, void* d_ws, size_t ws_size,
                              hipStream_t stream) {
  char* ws = (char*)d_ws;
  int*   flag    = (int*)(ws + 0);
  int*   cum     = (int*)(ws + 256);
  int*   melLenI = (int*)(ws + 33280);
  int*   idx     = (int*)(ws + 33536);
  u16*   canon   = (u16*)(ws + 295936);        // 11,654,960 B
  u16*   WF      = (u16*)(ws + 11950896);      //  5,308,416 B -> ~17.3 MB total

  float* o_main = (float*)d_out;               // (B, ML, H)
  float* o_pp   = o_main + 25165824;           // (B, ML)
  float* o_ep   = o_pp + 65536;                // (B, ML)
  float* o_ld   = o_ep + 65536;                // (B, T)
  float* o_dur  = o_ld + 8192;                 // (B, T)
  float* o_ml   = o_dur + 8192;                // (B,)
  float* o_mask = o_ml + 16;                   // (B, ML)

  Srcs S;
  static const int sel[29] = {0, 1, 2, 8, 9, 10, 11, 12, 13, 14, 15, 16, 17, 18, 19,
                              20, 21, 22, 23, 24, 25, 26, 27, 28, 29, 30, 31, 32, 33};
  for (int i = 0; i < 29; ++i) S.p[i] = d_in[sel[i]];
  const int* dur = (const int*)d_in[4];

  k_detect<<<1, 256, 0, stream>>>((const u32*)d_in[0], flag);
  k_canon<<<2048, 256, 0, stream>>>(S, canon, flag);
  k_wprep<<<1296, 256, 0, stream>>>(canon, WF);
  k_prep<<<16, 512, 0, stream>>>(dur, cum, melLenI, o_dur, o_ml, o_mask);
  k_idx<<<dim3(16, 16), 256, 0, stream>>>(cum, idx);

  const u16* X = canon + C_X;

  BranchArgs aDur = { nullptr, nullptr, nullptr,
                      WF + 0 * 884736, canon + C_DCB, canon + C_DCG, canon + C_DCBE,
                      canon + C_DLW, canon + C_DLB, o_ld };
  BranchArgs aPit = { canon + C_SP, canon + C_PC1W, canon + C_PC1B,
                      WF + 1 * 884736, canon + C_PCB, canon + C_PCG, canon + C_PCBE,
                      canon + C_PLW, canon + C_PLB, o_pp };
  BranchArgs aEne = { canon + C_SE, canon + C_EC1W, canon + C_EC1B,
                      WF + 2 * 884736, canon + C_ECB, canon + C_ECG, canon + C_ECBE,
                      canon + C_ELW, canon + C_ELB, o_ep };

  // duration predictor -> o_ld
  k_pred<512, 0, false><<<dim3(8, 16, 1), 512, 0, stream>>>(X, idx, melLenI, aDur, aDur);

  // pitch (z=0) + energy (z=1) -> o_pp / o_ep
  k_pred<4096, 1, true><<<dim3(64, 16, 2), 512, 0, stream>>>(X, idx, melLenI, aPit, aEne);

  // final assembly -> o_main
  k_out<<<24576, 256, 0, stream>>>(X, idx, melLenI, o_pp, o_ep,
      canon + C_PC2W, canon + C_PC2B, canon + C_EC2W, canon + C_EC2B, o_main);
}

// Round 6
// 454.848 us; speedup vs baseline: 20.3613x; 1.0150x over previous
//
#include <hip/hip_runtime.h>
#include <stdint.h>

// ---------------------------------------------------------------------------
// VarianceAdaptor on MI355X — round 6: XCD-residency block swizzle.
// r5 + bijective blockIdx remap so each XCD sees ONE branch's weights
// (1.77 MB) + a 4-batch X slice (~1.5 MB) => working set < 4 MB L2/XCD.
// (r5 counters: FETCH_SIZE 19.3 GB per merged k_pred = L2 thrash; the
// B-frag loads were L3-latency, unhideable by the 2-ahead prefetch.)
// ---------------------------------------------------------------------------

using u16 = unsigned short;
using u32 = unsigned int;
typedef __attribute__((ext_vector_type(8))) short bf16x8;
typedef __attribute__((ext_vector_type(4))) float f32x4;

#define DEV static __device__ __forceinline__

DEV float bf2f(u16 u) { union { u32 i; float f; } v; v.i = ((u32)u) << 16; return v.f; }
DEV u16 f2bf(float f) {
  union { float f; u32 i; } v; v.f = f;
  u32 x = v.i;
  return (u16)((x + 0x7FFFu + ((x >> 16) & 1u)) >> 16);   // RNE
}
DEV float lof(u32 p) { union { u32 i; float f; } v; v.i = p << 16; return v.f; }
DEV float hif(u32 p) { union { u32 i; float f; } v; v.i = p & 0xFFFF0000u; return v.f; }

// ---- canonical bf16 scratch layout (element offsets) ------------------------
static constexpr int C_X    = 0;
static constexpr int C_SP   = 3145728;
static constexpr int C_SE   = 3153920;
static constexpr int C_DCW  = 3162112;
static constexpr int C_DCB  = 4046848;
static constexpr int C_DCG  = 4047616;
static constexpr int C_DCBE = 4048384;
static constexpr int C_DLW  = 4049152;
static constexpr int C_DLB  = 4049536;
static constexpr int C_PCW  = 4049544;
static constexpr int C_PCB  = 4934280;
static constexpr int C_PCG  = 4935048;
static constexpr int C_PCBE = 4935816;
static constexpr int C_PLW  = 4936584;
static constexpr int C_PLB  = 4936968;
static constexpr int C_ECW  = 4936976;
static constexpr int C_ECB  = 5821712;
static constexpr int C_ECG  = 5822480;
static constexpr int C_ECBE = 5823248;
static constexpr int C_ELW  = 5824016;
static constexpr int C_ELB  = 5824400;
static constexpr int C_PC1W = 5824408;
static constexpr int C_PC1B = 5824792;
static constexpr int C_EC1W = 5825176;
static constexpr int C_EC1B = 5825560;
static constexpr int C_PC2W = 5825944;
static constexpr int C_PC2B = 5826328;
static constexpr int C_EC2W = 5826712;
static constexpr int C_EC2B = 5827096;
static constexpr int C_END  = 5827480;

__device__ const int g_off[30] = {
  C_X, C_SP, C_SE, C_DCW, C_DCB, C_DCG, C_DCBE, C_DLW, C_DLB,
  C_PCW, C_PCB, C_PCG, C_PCBE, C_PLW, C_PLB,
  C_ECW, C_ECB, C_ECG, C_ECBE, C_ELW, C_ELB,
  C_PC1W, C_PC1B, C_EC1W, C_EC1B, C_PC2W, C_PC2B, C_EC2W, C_EC2B, C_END };
__device__ const int g_act[29] = {
  3145728, 8192, 8192, 884736, 768, 768, 768, 384, 1,
  884736, 768, 768, 768, 384, 1,
  884736, 768, 768, 768, 384, 1,
  384, 384, 384, 384, 384, 384, 384, 384 };
__device__ const int g_wsrc[3] = { C_DCW, C_PCW, C_ECW };

struct Srcs { const void* p[29]; };

struct BranchArgs {
  const u16 *S, *C1W, *C1B, *WF, *CB, *CG, *CBE, *LW, *LB;
  float* predF;
};

// ---- dtype probe ------------------------------------------------------------
__global__ __launch_bounds__(256) void k_detect(const u32* __restrict__ x, int* __restrict__ flag) {
  __shared__ int sh[256];
  int t = threadIdx.x, cnt = 0;
  for (int i = t; i < 2048; i += 256) {
    u32 w = x[i];
    u32 lo = w & 0xFFFFu;
    float a = fabsf(lof(lo));
    if (lo == 0u || (a > 1e-5f && a < 1000.0f)) cnt++;
  }
  sh[t] = cnt; __syncthreads();
  for (int o = 128; o; o >>= 1) { if (t < o) sh[t] += sh[t + o]; __syncthreads(); }
  if (t == 0) *flag = (sh[0] > 1024) ? 1 : 0;
}

// ---- canonicalize all float inputs to one bf16 region -----------------------
__global__ __launch_bounds__(256) void k_canon(Srcs s, u16* __restrict__ canon, const int* __restrict__ flag) {
  int isbf = *flag;
  int stride = gridDim.x * blockDim.x;
  for (int i = blockIdx.x * blockDim.x + threadIdx.x; i < C_END; i += stride) {
    int lo = 0, hi = 29;
    while (hi - lo > 1) { int m = (lo + hi) >> 1; if (i >= g_off[m]) lo = m; else hi = m; }
    int li = i - g_off[lo];
    u16 v = 0;
    if (li < g_act[lo]) {
      if (isbf) v = ((const u16*)s.p[lo])[li];
      else      v = f2bf(((const float*)s.p[lo])[li]);
    }
    canon[i] = v;
  }
}

// ---- weight swizzle: (ls,kk,f) -> B-fragment-linear -------------------------
__global__ __launch_bounds__(256) void k_wprep(const u16* __restrict__ canon, u16* __restrict__ WF) {
  int g = blockIdx.x * 256 + threadIdx.x;       // 3*2*36*24*64 = 331776
  int l = g & 63; int rest = g >> 6;
  int nf = rest % 24; rest /= 24;
  int ks = rest % 36; rest /= 36;
  int ls = rest & 1;  int br = rest >> 1;
  if (br >= 3) return;
  const u16* src = canon + g_wsrc[br] + ls * 442368;
  int kk0 = ks * 32 + (l >> 4) * 8;
  int f = nf * 16 + (l & 15);
  u16* dst = WF + (size_t)br * 884736 + ((size_t)(ls * 36 + ks) * 24 + nf) * 512 + l * 8;
  #pragma unroll
  for (int j = 0; j < 8; ++j)
    dst[j] = src[(size_t)(kk0 + j) * 384 + f];
}

// ---- cumsum + f32 src_duration / mel_len / mel_mask outputs -----------------
__global__ __launch_bounds__(512) void k_prep(const int* __restrict__ dur, int* __restrict__ cum,
    int* __restrict__ melLenI, float* __restrict__ oDur, float* __restrict__ oML,
    float* __restrict__ oMask) {
  __shared__ int s[512];
  int b = blockIdx.x, t = threadIdx.x;
  int d = dur[b * 512 + t];
  s[t] = d; __syncthreads();
  for (int o = 1; o < 512; o <<= 1) {
    int v = s[t] + ((t >= o) ? s[t - o] : 0);
    __syncthreads(); s[t] = v; __syncthreads();
  }
  cum[b * 512 + t] = s[t];
  int mel = s[511];
  if (t == 0) { melLenI[b] = mel; oML[b] = (float)mel; }
  oDur[b * 512 + t] = (float)d;
  for (int j = t; j < 4096; j += 512) oMask[b * 4096 + j] = (j >= mel) ? 1.0f : 0.0f;
}

// ---- gather index -----------------------------------------------------------
__global__ __launch_bounds__(256) void k_idx(const int* __restrict__ cum, int* __restrict__ idx) {
  int b = blockIdx.y;
  int t = blockIdx.x * 256 + threadIdx.x;
  const int* c = cum + b * 512;
  int lo = 0, hi = 512;
  while (lo < hi) { int m = (lo + hi) >> 1; if (c[m] <= t) lo = m + 1; else hi = m; }
  if (lo > 511) lo = 511;
  idx[b * 4096 + t] = lo;
}

// ---- MFMA conv, software-pipelined: B 3-deep, A 2-deep ----------------------
template<int NMF>
DEV void do_conv(const u16* sb, const u16* __restrict__ wf,
                 f32x4 (&acc)[NMF][6], const int (&moff)[NMF],
                 int wn, int llo, int lhi, int l) {
  int arow = llo * 392 + lhi * 8;
  const u16* wb = wf + wn * 6 * 512 + l * 8;
  bf16x8 ab[2][NMF];
  bf16x8 bb[3][6];
  #pragma unroll
  for (int mf = 0; mf < NMF; ++mf)
    ab[0][mf] = *(const bf16x8*)(sb + moff[mf] * 392 + arow);           // ks=0
  #pragma unroll
  for (int nf = 0; nf < 6; ++nf) {
    bb[0][nf] = *(const bf16x8*)(wb + nf * 512);                         // ks=0
    bb[1][nf] = *(const bf16x8*)(wb + (24 + nf) * 512);                  // ks=1
  }
  #pragma unroll
  for (int ks = 0; ks < 36; ++ks) {
    if (ks + 2 < 36) {                       // prefetch B for ks+2 (L2 latency)
      #pragma unroll
      for (int nf = 0; nf < 6; ++nf)
        bb[(ks + 2) % 3][nf] = *(const bf16x8*)(wb + ((ks + 2) * 24 + nf) * 512);
    }
    if (ks + 1 < 36) {                       // prefetch A for ks+1 (LDS latency)
      int k1 = (ks + 1) / 12, c1 = ((ks + 1) % 12) * 32;
      #pragma unroll
      for (int mf = 0; mf < NMF; ++mf)
        ab[(ks + 1) & 1][mf] = *(const bf16x8*)(sb + (moff[mf] + k1) * 392 + c1 + arow);
    }
    __builtin_amdgcn_s_setprio(1);
    #pragma unroll
    for (int nf = 0; nf < 6; ++nf)
      #pragma unroll
      for (int mf = 0; mf < NMF; ++mf)
        acc[mf][nf] = __builtin_amdgcn_mfma_f32_16x16x32_bf16(ab[ks & 1][mf], bb[ks % 3][nf], acc[mf][nf], 0, 0, 0);
    __builtin_amdgcn_s_setprio(0);
  }
}

// ---- bias+relu+LN epilogue: in-reg stats, write normalized bf16 h to LDS ----
template<int NMF, bool ZERO_EDGE>
DEV void ln_epilogue(f32x4 (&acc)[NMF][6], const int (&moff)[NMF],
    const u16* __restrict__ CBp, const u16* __restrict__ CGp, const u16* __restrict__ CBEp,
    u16* sb, float* sp1, float* sp2, float* sm, float* sr,
    int wn, int llo, int lhi, int tid, int nrows, int t0, int L) {
  int colb = wn * 96 + llo;
  float bias[6], gv[6], bev[6];
  #pragma unroll
  for (int nf = 0; nf < 6; ++nf) {
    bias[nf] = bf2f(CBp[colb + nf * 16]);
    gv[nf]   = bf2f(CGp[colb + nf * 16]);
    bev[nf]  = bf2f(CBEp[colb + nf * 16]);
  }
  #pragma unroll
  for (int mf = 0; mf < NMF; ++mf)
    #pragma unroll
    for (int nf = 0; nf < 6; ++nf)
      #pragma unroll
      for (int r = 0; r < 4; ++r) {
        float v = acc[mf][nf][r] + bias[nf];
        acc[mf][nf][r] = v > 0.f ? v : 0.f;
      }
  #pragma unroll
  for (int mf = 0; mf < NMF; ++mf)
    #pragma unroll
    for (int r = 0; r < 4; ++r) {
      float p1 = 0.f, p2 = 0.f;
      #pragma unroll
      for (int nf = 0; nf < 6; ++nf) { float v = acc[mf][nf][r]; p1 += v; p2 += v * v; }
      #pragma unroll
      for (int m = 1; m <= 8; m <<= 1) { p1 += __shfl_xor(p1, m); p2 += __shfl_xor(p2, m); }
      if (llo == 0) {
        int row = moff[mf] + lhi * 4 + r;
        sp1[row * 4 + wn] = p1; sp2[row * 4 + wn] = p2;
      }
    }
  __syncthreads();
  if (tid < nrows) {
    float a = sp1[tid * 4] + sp1[tid * 4 + 1] + sp1[tid * 4 + 2] + sp1[tid * 4 + 3];
    float b = sp2[tid * 4] + sp2[tid * 4 + 1] + sp2[tid * 4 + 2] + sp2[tid * 4 + 3];
    float m = a * (1.f / 384.f);
    float var = b * (1.f / 384.f) - m * m; if (var < 0.f) var = 0.f;
    sm[tid] = m; sr[tid] = rsqrtf(var + 1e-5f);
  }
  __syncthreads();
  #pragma unroll
  for (int mf = 0; mf < NMF; ++mf)
    #pragma unroll
    for (int r = 0; r < 4; ++r) {
      int row = moff[mf] + lhi * 4 + r;
      float m = sm[row], rs = sr[row];
      bool valid = true;
      if (ZERO_EDGE) { int t = t0 - 1 + row; valid = (t >= 0) && (t < L); }
      #pragma unroll
      for (int nf = 0; nf < 6; ++nf) {
        float v = (acc[mf][nf][r] - m) * rs * gv[nf] + bev[nf];
        sb[row * 392 + colb + nf * 16] = valid ? f2bf(v) : (u16)0;
      }
    }
  __syncthreads();
}

// ---------------------------------------------------------------------------
// Fused MFMA predictor. 512 threads = 8 waves (2M x 4N). TT=64 rows/block.
// XCD-residency remap (assumes xcd = wgid % 8 round-robin):
//   MODE 1 (grid 64x16x2): xcd -> branch (z=xcd>>2) + 4-batch group (xcd&3)
//   MODE 0 (grid  8x16x1): xcd -> 2-batch group
// ---------------------------------------------------------------------------
template<int L, int MODE, bool MASK>
__global__ __launch_bounds__(512, 2) void k_pred(
    const u16* __restrict__ X, const int* __restrict__ idx,
    const int* __restrict__ melLenI, BranchArgs arg0, BranchArgs arg1) {
  __shared__ alignas(16) u16 s_buf[68 * 392];
  __shared__ float sp1[68 * 4], sp2[68 * 4], sm[68], sr[68];

  int b, t0, zz;
  if constexpr (MODE == 0) {
    int id = blockIdx.x + 8 * blockIdx.y;          // 0..127
    int xcd = id & 7, seq = id >> 3;               // seq 0..15
    b  = xcd * 2 + (seq & 1);
    t0 = (seq >> 1) * 64;                          // 0..7 tiles
    zz = 0;
  } else {
    int id = blockIdx.x + 64 * (blockIdx.y + 16 * blockIdx.z);  // 0..2047
    int xcd = id & 7, seq = id >> 3;               // seq 0..255
    zz = xcd >> 2;                                 // branch per XCD half
    b  = (xcd & 3) * 4 + (seq & 3);                // 4-batch group per XCD
    t0 = (seq >> 2) * 64;                          // 0..63 tiles
  }
  const BranchArgs& ba = zz ? arg1 : arg0;

  int tid = threadIdx.x;
  int w = tid >> 6, l = tid & 63;
  int llo = l & 15, lhi = l >> 4;
  int wm = w >> 2, wn = w & 3;
  int mel = melLenI[b];

  // --- provider: fill s_buf rows 0..67 (t = t0-2+r) ---
  if constexpr (MODE == 0) {
    for (int i = 0; i < 9; ++i) {
      int r = w + i * 8;
      if (r < 68) {
        int t = t0 - 2 + r;
        bool valid = (t >= 0) && (t < L);
        const u16* xr = X + ((size_t)b * L + (valid ? t : 0)) * 384;
        #pragma unroll
        for (int c = 0; c < 6; ++c) {
          int col = l + c * 64;
          s_buf[r * 392 + col] = valid ? xr[col] : (u16)0;
        }
      }
    }
  } else {
    float c1wf[6], c1bf[6];
    #pragma unroll
    for (int c = 0; c < 6; ++c) { c1wf[c] = bf2f(ba.C1W[l + c * 64]); c1bf[c] = bf2f(ba.C1B[l + c * 64]); }
    for (int i = 0; i < 9; ++i) {
      int r = w + i * 8;
      if (r < 68) {
        int t = t0 - 2 + r;
        bool valid = (t >= 0) && (t < L) && (t < mel);
        int j = valid ? idx[b * L + t] : 0;
        float sv = valid ? bf2f(ba.S[b * 512 + j]) : 0.f;
        const u16* xr = X + ((size_t)b * 512 + j) * 384;
        #pragma unroll
        for (int c = 0; c < 6; ++c) {
          int col = l + c * 64;
          float v = bf2f(xr[col]) + sv * c1wf[c] + c1bf[c];
          s_buf[r * 392 + col] = valid ? f2bf(v) : (u16)0;
        }
      }
    }
  }
  __syncthreads();

  // --- conv1 + LN (output rows 0..65 ~ t = t0-1+row) ---
  if (wm == 0) {
    const int moff[3] = {0, 16, 32};
    f32x4 acc[3][6];
    #pragma unroll
    for (int mf = 0; mf < 3; ++mf)
      #pragma unroll
      for (int nf = 0; nf < 6; ++nf) acc[mf][nf] = (f32x4){0.f, 0.f, 0.f, 0.f};
    do_conv<3>(s_buf, ba.WF, acc, moff, wn, llo, lhi, l);
    ln_epilogue<3, true>(acc, moff, ba.CB, ba.CG, ba.CBE, s_buf, sp1, sp2, sm, sr,
                         wn, llo, lhi, tid, 66, t0, L);
  } else {
    const int moff[2] = {48, 50};
    f32x4 acc[2][6];
    #pragma unroll
    for (int mf = 0; mf < 2; ++mf)
      #pragma unroll
      for (int nf = 0; nf < 6; ++nf) acc[mf][nf] = (f32x4){0.f, 0.f, 0.f, 0.f};
    do_conv<2>(s_buf, ba.WF, acc, moff, wn, llo, lhi, l);
    ln_epilogue<2, true>(acc, moff, ba.CB, ba.CG, ba.CBE, s_buf, sp1, sp2, sm, sr,
                         wn, llo, lhi, tid, 66, t0, L);
  }

  // --- conv2 + LN (output rows 0..63 ~ t = t0+row) ---
  {
    f32x4 acc[2][6];
    #pragma unroll
    for (int mf = 0; mf < 2; ++mf)
      #pragma unroll
      for (int nf = 0; nf < 6; ++nf) acc[mf][nf] = (f32x4){0.f, 0.f, 0.f, 0.f};
    if (wm == 0) {
      const int moff[2] = {0, 16};
      do_conv<2>(s_buf, ba.WF + 442368, acc, moff, wn, llo, lhi, l);
      ln_epilogue<2, false>(acc, moff, ba.CB + 384, ba.CG + 384, ba.CBE + 384, s_buf,
                            sp1, sp2, sm, sr, wn, llo, lhi, tid, 64, t0, L);
    } else {
      const int moff[2] = {32, 48};
      do_conv<2>(s_buf, ba.WF + 442368, acc, moff, wn, llo, lhi, l);
      ln_epilogue<2, false>(acc, moff, ba.CB + 384, ba.CG + 384, ba.CBE + 384, s_buf,
                            sp1, sp2, sm, sr, wn, llo, lhi, tid, 64, t0, L);
    }
  }

  // --- linear 384->1 (+ mask) ---
  {
    float lwv[6];
    #pragma unroll
    for (int c = 0; c < 6; ++c) lwv[c] = bf2f(ba.LW[l + c * 64]);
    float lb = bf2f(ba.LB[0]);
    for (int i = 0; i < 8; ++i) {
      int r = w + i * 8;
      float s = 0.f;
      #pragma unroll
      for (int c = 0; c < 6; ++c) s += bf2f(s_buf[r * 392 + l + c * 64]) * lwv[c];
      #pragma unroll
      for (int o = 32; o; o >>= 1) s += __shfl_xor(s, o);
      if (l == 0) {
        s += lb;
        int tt = t0 + r;
        if (MASK && tt >= mel) s = 0.f;
        ba.predF[b * L + tt] = s;
      }
    }
  }
}

// ---- final: out = x_exp + pp*pc2w + pc2b + ep*ec2w + ec2b  (f32 out) -------
__global__ __launch_bounds__(256) void k_out(const u16* __restrict__ X,
    const int* __restrict__ idx, const int* __restrict__ melLenI,
    const float* __restrict__ ppF, const float* __restrict__ epF,
    const u16* __restrict__ W1, const u16* __restrict__ B1,
    const u16* __restrict__ W2, const u16* __restrict__ B2,
    float* __restrict__ outp) {
  int i = blockIdx.x * 256 + threadIdx.x;      // float4 units
  int f4 = i % 96, row = i / 96;
  int b = row >> 12, t = row & 4095;
  float pp = ppF[row], ep = epF[row];
  uint2 w1 = *(const uint2*)(W1 + f4 * 4);
  uint2 b1 = *(const uint2*)(B1 + f4 * 4);
  uint2 w2 = *(const uint2*)(W2 + f4 * 4);
  uint2 b2 = *(const uint2*)(B2 + f4 * 4);
  float xv[4] = {0.f, 0.f, 0.f, 0.f};
  if (t < melLenI[b]) {
    int j = idx[row];
    uint2 xa = *(const uint2*)(X + (size_t)(b * 512 + j) * 384 + f4 * 4);
    xv[0] = lof(xa.x); xv[1] = hif(xa.x); xv[2] = lof(xa.y); xv[3] = hif(xa.y);
  }
  float4 o;
  o.x = xv[0] + pp * lof(w1.x) + lof(b1.x) + ep * lof(w2.x) + lof(b2.x);
  o.y = xv[1] + pp * hif(w1.x) + hif(b1.x) + ep * hif(w2.x) + hif(b2.x);
  o.z = xv[2] + pp * lof(w1.y) + lof(b1.y) + ep * lof(w2.y) + lof(b2.y);
  o.w = xv[3] + pp * hif(w1.y) + hif(b1.y) + ep * hif(w2.y) + hif(b2.y);
  *(float4*)(outp + (size_t)i * 4) = o;
}

// ---------------------------------------------------------------------------
extern "C" void kernel_launch(void* const* d_in, const int* in_sizes, int n_in,
                              void* d_out, int out_size, void* d_ws, size_t ws_size,
                              hipStream_t stream) {
  char* ws = (char*)d_ws;
  int*   flag    = (int*)(ws + 0);
  int*   cum     = (int*)(ws + 256);
  int*   melLenI = (int*)(ws + 33280);
  int*   idx     = (int*)(ws + 33536);
  u16*   canon   = (u16*)(ws + 295936);        // 11,654,960 B
  u16*   WF      = (u16*)(ws + 11950896);      //  5,308,416 B -> ~17.3 MB total

  float* o_main = (float*)d_out;               // (B, ML, H)
  float* o_pp   = o_main + 25165824;           // (B, ML)
  float* o_ep   = o_pp + 65536;                // (B, ML)
  float* o_ld   = o_ep + 65536;                // (B, T)
  float* o_dur  = o_ld + 8192;                 // (B, T)
  float* o_ml   = o_dur + 8192;                // (B,)
  float* o_mask = o_ml + 16;                   // (B, ML)

  Srcs S;
  static const int sel[29] = {0, 1, 2, 8, 9, 10, 11, 12, 13, 14, 15, 16, 17, 18, 19,
                              20, 21, 22, 23, 24, 25, 26, 27, 28, 29, 30, 31, 32, 33};
  for (int i = 0; i < 29; ++i) S.p[i] = d_in[sel[i]];
  const int* dur = (const int*)d_in[4];

  k_detect<<<1, 256, 0, stream>>>((const u32*)d_in[0], flag);
  k_canon<<<2048, 256, 0, stream>>>(S, canon, flag);
  k_wprep<<<1296, 256, 0, stream>>>(canon, WF);
  k_prep<<<16, 512, 0, stream>>>(dur, cum, melLenI, o_dur, o_ml, o_mask);
  k_idx<<<dim3(16, 16), 256, 0, stream>>>(cum, idx);

  const u16* X = canon + C_X;

  BranchArgs aDur = { nullptr, nullptr, nullptr,
                      WF + 0 * 884736, canon + C_DCB, canon + C_DCG, canon + C_DCBE,
                      canon + C_DLW, canon + C_DLB, o_ld };
  BranchArgs aPit = { canon + C_SP, canon + C_PC1W, canon + C_PC1B,
                      WF + 1 * 884736, canon + C_PCB, canon + C_PCG, canon + C_PCBE,
                      canon + C_PLW, canon + C_PLB, o_pp };
  BranchArgs aEne = { canon + C_SE, canon + C_EC1W, canon + C_EC1B,
                      WF + 2 * 884736, canon + C_ECB, canon + C_ECG, canon + C_ECBE,
                      canon + C_ELW, canon + C_ELB, o_ep };

  // duration predictor -> o_ld
  k_pred<512, 0, false><<<dim3(8, 16, 1), 512, 0, stream>>>(X, idx, melLenI, aDur, aDur);

  // pitch (z=0) + energy (z=1) -> o_pp / o_ep
  k_pred<4096, 1, true><<<dim3(64, 16, 2), 512, 0, stream>>>(X, idx, melLenI, aPit, aEne);

  // final assembly -> o_main
  k_out<<<24576, 256, 0, stream>>>(X, idx, melLenI, o_pp, o_ep,
      canon + C_PC2W, canon + C_PC2B, canon + C_EC2W, canon + C_EC2B, o_main);
}